// Round 18
// baseline (321.213 us; speedup 1.0000x reference)
//
#include <hip/hip_runtime.h>
#include <math.h>

#define N_NODES 50000
#define N_EDGES 800000
#define DIN 128
#define DH 128
#define EA_C 50
#define DE 100
#define FM 228      // DIN + DE
#define AS 320      // A stride in u32
#define WKL 384     // logical K (W stride)
#define BM 32       // GEMM row tile
#define BN_EPS 1e-5f
#define SCAN_NB ((N_NODES + 255) / 256)   // 196
#define GBLK ((N_NODES + BM - 1) / BM)    // 1563
#define GSZ  ((N_NODES + 7) / 8)          // 6250 rows per XCD partition

typedef __attribute__((ext_vector_type(8))) short short8;
typedef __attribute__((ext_vector_type(4))) short s16x4;
typedef __attribute__((ext_vector_type(4))) float f32x4;
typedef unsigned int u32;
typedef unsigned short u16;

// ---- bf16 hi/lo packing ----
__device__ inline u16 f2bf(float f) {
  u32 u = __float_as_uint(f);
  u32 r = (u + 0x7fffu + ((u >> 16) & 1u)) >> 16;
  return (u16)r;
}
__device__ inline float bf2f(u16 h) { return __uint_as_float(((u32)h) << 16); }
__device__ inline u32 pack_hl(float v) {
  u16 hi = f2bf(v);
  u16 lo = f2bf(v - bf2f(hi));
  return (u32)hi | ((u32)lo << 16);
}
__device__ inline float unpack_hl(u32 p) {
  return bf2f((u16)(p & 0xffffu)) + bf2f((u16)(p >> 16));
}

// ---------------- CSR build ----------------
// rec.x = col*AS (24 bits) | (attr*2+dir)<<24 ; rec.y = log(t+1)
__global__ void k_count(const int* __restrict__ row, const int* __restrict__ col,
                        const int* __restrict__ attr, const int* __restrict__ dire,
                        const int* __restrict__ tim,
                        int* __restrict__ counts, uint2* __restrict__ pay8) {
  int e = blockIdx.x * 256 + threadIdx.x;
  if (e < N_EDGES) {
    atomicAdd(&counts[row[e]], 1);
    uint2 rec;
    rec.x = (u32)col[e] * AS | (((u32)attr[e] * 2 + (u32)dire[e]) << 24);
    rec.y = __float_as_uint(__logf((float)tim[e] + 1.0f));
    pay8[e] = rec;
  }
}

// combined embedding table
__global__ void k_ecomb(const float* __restrict__ emb_type, const float* __restrict__ emb_dir,
                        float* __restrict__ ec) {
  int i = blockIdx.x * 256 + threadIdx.x;
  if (i >= 24 * EA_C) return;
  int combo = i / EA_C, l = i - combo * EA_C;
  ec[i] = emb_type[(combo >> 1) * EA_C + l] + emb_dir[(combo & 1) * EA_C + l];
}

__global__ void k_scan_a(const int* __restrict__ counts, int* __restrict__ incl,
                         int* __restrict__ bsum) {
  __shared__ int buf[256];
  int i = blockIdx.x * 256 + threadIdx.x;
  int v = (i < N_NODES) ? counts[i] : 0;
  buf[threadIdx.x] = v;
  __syncthreads();
#pragma unroll
  for (int off = 1; off < 256; off <<= 1) {
    int t = (threadIdx.x >= off) ? buf[threadIdx.x - off] : 0;
    __syncthreads();
    buf[threadIdx.x] += t;
    __syncthreads();
  }
  if (i < N_NODES) incl[i] = buf[threadIdx.x];
  if (threadIdx.x == 255) bsum[blockIdx.x] = buf[255];
}

__global__ void k_scan_b(const int* __restrict__ bsum, int* __restrict__ boff,
                         int* __restrict__ row_ptr) {
  __shared__ int buf[256];
  int v = (threadIdx.x < SCAN_NB) ? bsum[threadIdx.x] : 0;
  buf[threadIdx.x] = v;
  __syncthreads();
#pragma unroll
  for (int off = 1; off < 256; off <<= 1) {
    int t = (threadIdx.x >= off) ? buf[threadIdx.x - off] : 0;
    __syncthreads();
    buf[threadIdx.x] += t;
    __syncthreads();
  }
  if (threadIdx.x < SCAN_NB) boff[threadIdx.x] = buf[threadIdx.x] - v;
  if (threadIdx.x == 255) row_ptr[N_NODES] = buf[255];
}

__global__ void k_scan_c(const int* __restrict__ incl, const int* __restrict__ counts,
                         const int* __restrict__ boff, int* __restrict__ row_ptr,
                         int* __restrict__ cursor) {
  int i = blockIdx.x * 256 + threadIdx.x;
  if (i < N_NODES) {
    int p = incl[i] - counts[i] + boff[blockIdx.x];
    row_ptr[i] = p;
    cursor[i] = p;
  }
}

// XCD-partitioned scatter (r12)
__global__ void k_fill(const int* __restrict__ row, const uint2* __restrict__ pay8,
                       int* __restrict__ cursor, uint2* __restrict__ er_s) {
  int b = blockIdx.x;
  int g = b & 7, c = b >> 3;
  int e = c * 256 + threadIdx.x;
  if (e >= N_EDGES) return;
  int r = row[e];
  int lo = g * GSZ;
  if (r < lo || r >= lo + GSZ) return;
  int slot = atomicAdd(&cursor[r], 1);
  er_s[slot] = pay8[e];
}

// ---------------- x -> A h16 plane (bf16), x4 vectorized ----------------
__global__ void k_conv_x(const float* __restrict__ x, u32* __restrict__ A) {
  int idx = blockIdx.x * 256 + threadIdx.x;
  if (idx >= N_NODES * 32) return;
  int n = idx >> 5, c4 = (idx & 31) << 2;
  float4 v = *reinterpret_cast<const float4*>(x + (size_t)n * DH + c4);
  uint2 o;
  o.x = (u32)f2bf(v.x) | ((u32)f2bf(v.y) << 16);
  o.y = (u32)f2bf(v.z) | ((u32)f2bf(v.w) << 16);
  *reinterpret_cast<uint2*>(A + (size_t)n * AS + 128 + (c4 >> 1)) = o;
}

// ---------------- FUSED layer-0 aggregation: h-agg + ea + et -----------------
__global__ void k_aggHE(const int* __restrict__ row_ptr, const uint2* __restrict__ er_s,
                        const float* __restrict__ ec,
                        const float* __restrict__ w_t, const float* __restrict__ b_t,
                        u32* __restrict__ A) {
  int wave = threadIdx.x >> 6, lane = threadIdx.x & 63;
  int n = blockIdx.x * 4 + wave;
  if (n >= N_NODES) return;
  int s = __builtin_amdgcn_readfirstlane(row_ptr[n]);
  int epos = __builtin_amdgcn_readfirstlane(row_ptr[n + 1]);
  bool ew = lane < EA_C;
  float wt = ew ? w_t[lane] : 0.f;
  float bt = ew ? b_t[lane] : 0.f;
  float ax = 0.f, ay = 0.f, ea = 0.f, et = 0.f;
  int p = s;
  for (; p + 3 < epos; p += 4) {
    uint2 r0 = er_s[p], r1 = er_s[p + 1], r2 = er_s[p + 2], r3 = er_s[p + 3];
    u32 v0 = A[(r0.x & 0xFFFFFFu) + 128 + lane];
    u32 v1 = A[(r1.x & 0xFFFFFFu) + 128 + lane];
    u32 v2 = A[(r2.x & 0xFFFFFFu) + 128 + lane];
    u32 v3 = A[(r3.x & 0xFFFFFFu) + 128 + lane];
    if (ew) {
      ea += ec[(r0.x >> 24) * EA_C + lane] + ec[(r1.x >> 24) * EA_C + lane];
      ea += ec[(r2.x >> 24) * EA_C + lane] + ec[(r3.x >> 24) * EA_C + lane];
      et += __cosf(__uint_as_float(r0.y) * wt + bt) + __cosf(__uint_as_float(r1.y) * wt + bt);
      et += __cosf(__uint_as_float(r2.y) * wt + bt) + __cosf(__uint_as_float(r3.y) * wt + bt);
    }
    ax += bf2f((u16)(v0 & 0xffffu)) + bf2f((u16)(v1 & 0xffffu)) +
          bf2f((u16)(v2 & 0xffffu)) + bf2f((u16)(v3 & 0xffffu));
    ay += bf2f((u16)(v0 >> 16)) + bf2f((u16)(v1 >> 16)) +
          bf2f((u16)(v2 >> 16)) + bf2f((u16)(v3 >> 16));
  }
  for (; p < epos; ++p) {
    uint2 r0 = er_s[p];
    u32 v0 = A[(r0.x & 0xFFFFFFu) + 128 + lane];
    if (ew) {
      ea += ec[(r0.x >> 24) * EA_C + lane];
      et += __cosf(__uint_as_float(r0.y) * wt + bt);
    }
    ax += bf2f((u16)(v0 & 0xffffu));
    ay += bf2f((u16)(v0 >> 16));
  }
  uint2 o; o.x = pack_hl(ax); o.y = pack_hl(ay);
  *reinterpret_cast<uint2*>(A + (size_t)n * AS + 2 * lane) = o;
  if (ew) {
    A[(size_t)n * AS + 192 + lane] = pack_hl(ea);
    A[(size_t)n * AS + 242 + lane] = pack_hl(et);
  } else {
    int l = lane - EA_C;
    A[(size_t)n * AS + 292 + l] = 0u;
    A[(size_t)n * AS + 306 + l] = 0u;
  }
}

// ---------------- lean neighbor aggregation (layer 1), 8-edge unroll ---------
__global__ void k_aggH(const int* __restrict__ row_ptr, const uint2* __restrict__ er_s,
                       u32* __restrict__ A) {
  int wave = threadIdx.x >> 6, lane = threadIdx.x & 63;
  int n = blockIdx.x * 4 + wave;
  if (n >= N_NODES) return;
  int s = __builtin_amdgcn_readfirstlane(row_ptr[n]);
  int epos = __builtin_amdgcn_readfirstlane(row_ptr[n + 1]);
  float ax = 0.f, ay = 0.f;
  int p = s;
  for (; p + 7 < epos; p += 8) {
    u32 v[8];
#pragma unroll
    for (int j = 0; j < 8; ++j) v[j] = A[(er_s[p + j].x & 0xFFFFFFu) + 128 + lane];
#pragma unroll
    for (int j = 0; j < 8; ++j) {
      ax += bf2f((u16)(v[j] & 0xffffu));
      ay += bf2f((u16)(v[j] >> 16));
    }
  }
  for (; p < epos; ++p) {
    u32 v = A[(er_s[p].x & 0xFFFFFFu) + 128 + lane];
    ax += bf2f((u16)(v & 0xffffu));
    ay += bf2f((u16)(v >> 16));
  }
  uint2 o; o.x = pack_hl(ax); o.y = pack_hl(ay);
  *reinterpret_cast<uint2*>(A + (size_t)n * AS + 2 * lane) = o;
}

// ---------------- weight prep ----------------
__global__ void k_wprep(const float* __restrict__ Wm, const float* __restrict__ Wr,
                        u32* __restrict__ WT2) {
  int idx = blockIdx.x * 256 + threadIdx.x;
  if (idx >= DH * WKL) return;
  int o = idx / WKL, k = idx - o * WKL;
  float v;
  if (k < 128) v = 0.5f * Wm[o * FM + k];
  else if (k < 256) v = Wr[o * DIN + (k - 128)];
  else if (k < 356) v = 0.5f * Wm[o * FM + (k - 128)];
  else v = 0.f;
  WT2[idx] = pack_hl(v);
}

__global__ void k_bias(const float* __restrict__ bm, const float* __restrict__ br,
                       float* __restrict__ bv) {
  int o = threadIdx.x;
  if (o < DH) bv[o] = 0.5f * bm[o] + br[o];
}

// ---------------- MFMA GEMM: BM=32, granule LDS, register prefetch -----------
__global__ __launch_bounds__(256) void k_mfma(const u32* __restrict__ A,
                                              const u32* __restrict__ W,
                                              const float* __restrict__ bv,
                                              float* __restrict__ out,
                                              float* __restrict__ pstat) {
  __shared__ u16 Ah[4][BM][8], Al[4][BM][8];     // 2KB each
  __shared__ u16 Wh[4][128][8], Wl[4][128][8];   // 8KB each
  __shared__ float sred[4][128], qred[4][128];
  int tid = threadIdx.x;
  int wv = tid >> 6, ln = tid & 63;
  int rw = wv >> 1, cw = wv & 1;
  int colb = ln & 15, fq = ln >> 4;
  int node0 = blockIdx.x * BM;

  {
    float* sp = &sred[0][0]; float* qp = &qred[0][0];
    sp[tid] = 0.f; sp[tid + 256] = 0.f;
    qp[tid] = 0.f; qp[tid + 256] = 0.f;
  }

  f32x4 acc[4];
#pragma unroll
  for (int nt = 0; nt < 4; ++nt) acc[nt] = (f32x4){0.f, 0.f, 0.f, 0.f};

  int ar = tid >> 3, aq = tid & 7;
  int an = node0 + ar;
  bool valid = an < N_NODES;
  const u32* aptr = A + (size_t)an * AS;
  int wc = tid >> 1, wk = (tid & 1) * 16;
  int wg = (tid & 1) * 2;
  const u32* wptr = W + (size_t)wc * WKL + wk;

  const u16* afh = &Ah[fq][(rw << 4) + colb][0];
  const u16* afl = &Al[fq][(rw << 4) + colb][0];

  uint4 a0n, w0n, w1n, w2n, w3n;

#define LOADC(CH, A0, W0, W1, W2, W3)                                     \
  {                                                                       \
    const int kl_ = (CH) * 32;                                            \
    A0 = make_uint4(0, 0, 0, 0);                                          \
    if ((CH) < 4 || (CH) >= 8) {                                          \
      int acol_ = ((CH) < 4 ? kl_ : kl_ - 64) + aq * 4;                   \
      if (valid) A0 = *reinterpret_cast<const uint4*>(aptr + acol_);      \
    } else if (aq < 4) {                                                  \
      int acol_ = 128 + ((kl_ - 128) >> 1) + aq * 4;                      \
      if (valid) A0 = *reinterpret_cast<const uint4*>(aptr + acol_);      \
    }                                                                     \
    W0 = *reinterpret_cast<const uint4*>(wptr + kl_);                     \
    W1 = *reinterpret_cast<const uint4*>(wptr + kl_ + 4);                 \
    W2 = *reinterpret_cast<const uint4*>(wptr + kl_ + 8);                 \
    W3 = *reinterpret_cast<const uint4*>(wptr + kl_ + 12);                \
  }

  LOADC(0, a0n, w0n, w1n, w2n, w3n);

#pragma unroll
  for (int ch = 0; ch < 12; ++ch) {
    const bool ph2 = (ch >= 4 && ch < 8);
    uint4 a0 = a0n, w0 = w0n, w1 = w1n, w2 = w2n, w3 = w3n;
    if (ch < 11) LOADC(ch + 1, a0n, w0n, w1n, w2n, w3n);

    __syncthreads();   // previous chunk's LDS reads done

    if (!ph2) {
      u32 va[4] = {a0.x, a0.y, a0.z, a0.w};
      s16x4 h, l;
#pragma unroll
      for (int j = 0; j < 4; ++j) { h[j] = (short)(va[j] & 0xffffu); l[j] = (short)(va[j] >> 16); }
      *reinterpret_cast<s16x4*>(&Ah[aq >> 1][ar][(aq & 1) * 4]) = h;
      *reinterpret_cast<s16x4*>(&Al[aq >> 1][ar][(aq & 1) * 4]) = l;
    } else if (aq < 4) {
      *reinterpret_cast<short8*>(&Ah[aq][ar][0]) = *reinterpret_cast<const short8*>(&a0);
    }
    {
      u32 vw[16] = {w0.x, w0.y, w0.z, w0.w, w1.x, w1.y, w1.z, w1.w,
                    w2.x, w2.y, w2.z, w2.w, w3.x, w3.y, w3.z, w3.w};
      short8 h0, l0, h1, l1;
#pragma unroll
      for (int j = 0; j < 8; ++j) {
        h0[j] = (short)(vw[j] & 0xffffu);     l0[j] = (short)(vw[j] >> 16);
        h1[j] = (short)(vw[j + 8] & 0xffffu); l1[j] = (short)(vw[j + 8] >> 16);
      }
      *reinterpret_cast<short8*>(&Wh[wg][wc][0]) = h0;
      *reinterpret_cast<short8*>(&Wh[wg + 1][wc][0]) = h1;
      *reinterpret_cast<short8*>(&Wl[wg][wc][0]) = l0;
      *reinterpret_cast<short8*>(&Wl[wg + 1][wc][0]) = l1;
    }

    __syncthreads();   // LDS writes visible

    short8 ah = *reinterpret_cast<const short8*>(afh);
    short8 al = *reinterpret_cast<const short8*>(afl);
#pragma unroll
    for (int nt = 0; nt < 4; ++nt) {
      int wrow = (cw << 6) + nt * 16 + colb;
      short8 bh = *reinterpret_cast<const short8*>(&Wh[fq][wrow][0]);
      short8 bl = *reinterpret_cast<const short8*>(&Wl[fq][wrow][0]);
      acc[nt] = __builtin_amdgcn_mfma_f32_16x16x32_bf16(ah, bh, acc[nt], 0, 0, 0);
      if (!ph2) acc[nt] = __builtin_amdgcn_mfma_f32_16x16x32_bf16(al, bh, acc[nt], 0, 0, 0);
      acc[nt] = __builtin_amdgcn_mfma_f32_16x16x32_bf16(ah, bl, acc[nt], 0, 0, 0);
    }
  }
#undef LOADC

  // epilogue: out + bias; BN partials shuffle-reduced, NO atomics
  int rbase = node0 + (rw << 4) + (fq << 2);
#pragma unroll
  for (int nt = 0; nt < 4; ++nt) {
    int col = (cw << 6) + nt * 16 + colb;
    float bb = bv[col];
    float s = 0.f, q = 0.f;
#pragma unroll
    for (int r = 0; r < 4; ++r) {
      int n = rbase + r;
      if (n < N_NODES) {
        float v = acc[nt][r] + bb;
        out[(size_t)n * DH + col] = v;
        s += v; q += v * v;
      }
    }
    s += __shfl_xor(s, 16, 64); s += __shfl_xor(s, 32, 64);
    q += __shfl_xor(q, 16, 64); q += __shfl_xor(q, 32, 64);
    if (fq == 0) { sred[wv][col] = s; qred[wv][col] = q; }
  }
  __syncthreads();
  if (tid < 128) {
    float s = sred[0][tid] + sred[1][tid] + sred[2][tid] + sred[3][tid];
    float q = qred[0][tid] + qred[1][tid] + qred[2][tid] + qred[3][tid];
    pstat[(size_t)blockIdx.x * 256 + tid] = s;
    pstat[(size_t)blockIdx.x * 256 + 128 + tid] = q;
  }
}

// reduce per-block partials -> stats[256]
__global__ void k_bnred(const float* __restrict__ pstat, float* __restrict__ stats) {
  __shared__ float red[256];
  int slot = blockIdx.x;
  float s = 0.f;
  for (int b = threadIdx.x; b < GBLK; b += 256) s += pstat[(size_t)b * 256 + slot];
  red[threadIdx.x] = s;
  __syncthreads();
  for (int off = 128; off >= 1; off >>= 1) {
    if (threadIdx.x < off) red[threadIdx.x] += red[threadIdx.x + off];
    __syncthreads();
  }
  if (threadIdx.x == 0) stats[slot] = red[0];
}

// BN + ELU -> h16 plane (bf16), x4 vectorized
__global__ void k_bnapply(const float* __restrict__ x, const float* __restrict__ stats,
                          const float* __restrict__ g, const float* __restrict__ be,
                          u32* __restrict__ A) {
  int idx = blockIdx.x * 256 + threadIdx.x;
  if (idx >= N_NODES * 32) return;
  int n = idx >> 5, c4 = (idx & 31) << 2;
  float4 v = *reinterpret_cast<const float4*>(x + (size_t)n * DH + c4);
  float4 sm = *reinterpret_cast<const float4*>(stats + c4);
  float4 sq = *reinterpret_cast<const float4*>(stats + 128 + c4);
  float4 gg = *reinterpret_cast<const float4*>(g + c4);
  float4 bb = *reinterpret_cast<const float4*>(be + c4);
  float vv[4] = {v.x, v.y, v.z, v.w};
  float mm[4] = {sm.x, sm.y, sm.z, sm.w};
  float qq[4] = {sq.x, sq.y, sq.z, sq.w};
  float ga[4] = {gg.x, gg.y, gg.z, gg.w};
  float ba[4] = {bb.x, bb.y, bb.z, bb.w};
  u16 ob[4];
#pragma unroll
  for (int j = 0; j < 4; ++j) {
    float mu = mm[j] * (1.0f / N_NODES);
    float var = qq[j] * (1.0f / N_NODES) - mu * mu;
    float y = (vv[j] - mu) * rsqrtf(var + BN_EPS) * ga[j] + ba[j];
    y = y > 0.f ? y : expm1f(y);
    ob[j] = f2bf(y);
  }
  uint2 o;
  o.x = (u32)ob[0] | ((u32)ob[1] << 16);
  o.y = (u32)ob[2] | ((u32)ob[3] << 16);
  *reinterpret_cast<uint2*>(A + (size_t)n * AS + 128 + (c4 >> 1)) = o;
}

// ---------------- layer 2 (project-first, dout=2) ----------------
__global__ void k_l2_dense(const u32* __restrict__ A,
                           const float* __restrict__ Wm2, const float* __restrict__ bm2,
                           const float* __restrict__ Wr2, const float* __restrict__ br2,
                           float* __restrict__ val, float* __restrict__ pm) {
  int wave = threadIdx.x >> 6, lane = threadIdx.x & 63;
  int n = blockIdx.x * 4 + wave;
  if (n >= N_NODES) return;
  const u32* ar = A + (size_t)n * AS;
  const u16* h16 = (const u16*)(ar + 128);
  float h0 = bf2f(h16[lane]);
  float h1 = bf2f(h16[lane + 64]);
  float e0 = unpack_hl(ar[192 + lane]);
  float e1 = (lane < DE - 64) ? unpack_hl(ar[256 + lane]) : 0.f;

  float pm0 = h0 * Wm2[lane] + h1 * Wm2[lane + 64];
  float pm1 = h0 * Wm2[FM + lane] + h1 * Wm2[FM + lane + 64];
  float ve0 = e0 * Wm2[DIN + lane] + ((lane < DE - 64) ? e1 * Wm2[DIN + lane + 64] : 0.f);
  float ve1 = e0 * Wm2[FM + DIN + lane] + ((lane < DE - 64) ? e1 * Wm2[FM + DIN + lane + 64] : 0.f);
  float pr0 = h0 * Wr2[lane] + h1 * Wr2[lane + 64];
  float pr1 = h0 * Wr2[DH + lane] + h1 * Wr2[DH + lane + 64];

#pragma unroll
  for (int m = 32; m >= 1; m >>= 1) {
    pm0 += __shfl_xor(pm0, m, 64); pm1 += __shfl_xor(pm1, m, 64);
    ve0 += __shfl_xor(ve0, m, 64); ve1 += __shfl_xor(ve1, m, 64);
    pr0 += __shfl_xor(pr0, m, 64); pr1 += __shfl_xor(pr1, m, 64);
  }
  if (lane == 0) {
    val[n * 2 + 0] = 0.5f * (ve0 + bm2[0]) + pr0 + br2[0];
    val[n * 2 + 1] = 0.5f * (ve1 + bm2[1]) + pr1 + br2[1];
    pm[n * 2 + 0] = pm0;
    pm[n * 2 + 1] = pm1;
  }
}

__global__ void k_agg2(const int* __restrict__ row_ptr, const uint2* __restrict__ er_s,
                       const float* __restrict__ pm, float* __restrict__ val) {
  int n = blockIdx.x * 256 + threadIdx.x;
  if (n >= N_NODES) return;
  float a0 = 0.f, a1 = 0.f;
  int s = row_ptr[n], e = row_ptr[n + 1];
  for (int p = s; p < e; ++p) {
    u32 coff = er_s[p].x & 0xFFFFFFu;
    u32 c = __umulhi(coff >> 6, 0xCCCCCCCDu) >> 2;   // (coff/64)/5 = col
    a0 += pm[c * 2]; a1 += pm[c * 2 + 1];
  }
  val[n * 2] += 0.5f * a0;
  val[n * 2 + 1] += 0.5f * a1;
}

__global__ void k_bnstats2(const float* __restrict__ val, float* __restrict__ s4) {
  float s0 = 0.f, q0 = 0.f, s1 = 0.f, q1 = 0.f;
  for (int n = blockIdx.x * 256 + threadIdx.x; n < N_NODES; n += gridDim.x * 256) {
    float v0 = val[n * 2], v1 = val[n * 2 + 1];
    s0 += v0; q0 += v0 * v0; s1 += v1; q1 += v1 * v1;
  }
  __shared__ float b[256][4];
  b[threadIdx.x][0] = s0; b[threadIdx.x][1] = q0;
  b[threadIdx.x][2] = s1; b[threadIdx.x][3] = q1;
  __syncthreads();
  for (int off = 128; off >= 1; off >>= 1) {
    if (threadIdx.x < off)
      for (int j = 0; j < 4; ++j) b[threadIdx.x][j] += b[threadIdx.x + off][j];
    __syncthreads();
  }
  if (threadIdx.x == 0)
    for (int j = 0; j < 4; ++j) atomicAdd(&s4[j], b[0][j]);
}

__global__ void k_final(const float* __restrict__ val, const float* __restrict__ s4,
                        const float* __restrict__ g2, const float* __restrict__ be2,
                        float* __restrict__ out) {
  int n = blockIdx.x * 256 + threadIdx.x;
  if (n >= N_NODES) return;
  float mu0 = s4[0] * (1.f / N_NODES), var0 = s4[1] * (1.f / N_NODES) - mu0 * mu0;
  float mu1 = s4[2] * (1.f / N_NODES), var1 = s4[3] * (1.f / N_NODES) - mu1 * mu1;
  float y0 = (val[n * 2] - mu0) * rsqrtf(var0 + BN_EPS) * g2[0] + be2[0];
  float y1 = (val[n * 2 + 1] - mu1) * rsqrtf(var1 + BN_EPS) * g2[1] + be2[1];
  float m = fmaxf(y0, y1);
  float lse = m + __logf(__expf(y0 - m) + __expf(y1 - m));
  out[n * 2] = y0 - lse;
  out[n * 2 + 1] = y1 - lse;
}

// ---------------- launch ----------------
extern "C" void kernel_launch(void* const* d_in, const int* in_sizes, int n_in,
                              void* d_out, int out_size, void* d_ws, size_t ws_size,
                              hipStream_t stream) {
  (void)in_sizes; (void)n_in; (void)out_size; (void)ws_size;
  const float* x        = (const float*)d_in[0];
  const int*   eidx     = (const int*)d_in[1];
  const int*   row      = eidx;
  const int*   col      = eidx + N_EDGES;
  const int*   attr     = (const int*)d_in[2];
  const int*   tim      = (const int*)d_in[3];
  const int*   dire     = (const int*)d_in[4];
  const float* emb_type = (const float*)d_in[5];
  const float* emb_dir  = (const float*)d_in[6];
  const float* w_t      = (const float*)d_in[7];
  const float* b_t      = (const float*)d_in[8];
  const float* Wm[3] = {(const float*)d_in[9],  (const float*)d_in[15], (const float*)d_in[21]};
  const float* bm[3] = {(const float*)d_in[10], (const float*)d_in[16], (const float*)d_in[22]};
  const float* Wr[3] = {(const float*)d_in[11], (const float*)d_in[17], (const float*)d_in[23]};
  const float* br[3] = {(const float*)d_in[12], (const float*)d_in[18], (const float*)d_in[24]};
  const float* g[3]  = {(const float*)d_in[13], (const float*)d_in[19], (const float*)d_in[25]};
  const float* be[3] = {(const float*)d_in[14], (const float*)d_in[20], (const float*)d_in[26]};
  float* out = (float*)d_out;

  // workspace layout (~99 MB)
  char* p = (char*)d_ws;
  u32* A     = (u32*)p;   p += sizeof(u32) * (size_t)N_NODES * AS;    // 64 MB
  float* gout = (float*)p; p += sizeof(float) * (size_t)N_NODES * DH; // 25.6 MB
  uint2* er_s = (uint2*)p; p += sizeof(uint2) * (size_t)N_EDGES;      // 6.4 MB
  float* pstat = (float*)p; p += sizeof(float) * (size_t)GBLK * 256;  // 1.6 MB
  u32* WT2[2];
  WT2[0] = (u32*)p; p += sizeof(u32) * DH * WKL;
  WT2[1] = (u32*)p; p += sizeof(u32) * DH * WKL;
  float* bv[2];
  bv[0] = (float*)p; p += sizeof(float) * DH;
  bv[1] = (float*)p; p += sizeof(float) * DH;
  float* ec   = (float*)p;  p += sizeof(float) * 24 * EA_C;
  float* val  = (float*)p;  p += sizeof(float) * (size_t)N_NODES * 2;
  float* pmb  = (float*)p;  p += sizeof(float) * (size_t)N_NODES * 2;
  float* stats = (float*)p; p += sizeof(float) * 520;
  int* counts  = (int*)p;   p += sizeof(int) * N_NODES;
  int* cursor  = (int*)p;   p += sizeof(int) * N_NODES;
  int* row_ptr = (int*)p;   p += sizeof(int) * (N_NODES + 1);
  int* incl    = (int*)p;   p += sizeof(int) * N_NODES;
  int* bsum    = (int*)p;   p += sizeof(int) * SCAN_NB;
  int* boff    = (int*)p;   p += sizeof(int) * SCAN_NB;

  uint2* pay8 = (uint2*)gout;   // aliases gout (consumed by k_fill before k_mfma writes)

  const int EB = (N_EDGES + 255) / 256;      // 3125
  const int NB = (N_NODES + 255) / 256;      // 196
  const int AB = (N_NODES + 3) / 4;          // 12500
  const int XB4 = (N_NODES * 32 + 255) / 256; // 6250
  const int WB = (DH * WKL + 255) / 256;     // 192

  hipMemsetAsync(counts, 0, sizeof(int) * N_NODES, stream);
  hipMemsetAsync(stats, 0, sizeof(float) * 520, stream);

  // CSR
  k_count<<<EB, 256, 0, stream>>>(row, col, attr, dire, tim, counts, pay8);
  k_ecomb<<<5, 256, 0, stream>>>(emb_type, emb_dir, ec);
  k_scan_a<<<SCAN_NB, 256, 0, stream>>>(counts, incl, bsum);
  k_scan_b<<<1, 256, 0, stream>>>(bsum, boff, row_ptr);
  k_scan_c<<<SCAN_NB, 256, 0, stream>>>(incl, counts, boff, row_ptr, cursor);
  k_fill<<<8 * EB, 256, 0, stream>>>(row, pay8, cursor, er_s);

  // weight prep
  for (int l = 0; l < 2; ++l) {
    k_wprep<<<WB, 256, 0, stream>>>(Wm[l], Wr[l], WT2[l]);
    k_bias<<<1, 128, 0, stream>>>(bm[l], br[l], bv[l]);
  }

  // x -> h16 plane
  k_conv_x<<<XB4, 256, 0, stream>>>(x, A);

  // layer 0: fused h-agg + edge-feature agg
  k_aggHE<<<AB, 256, 0, stream>>>(row_ptr, er_s, ec, w_t, b_t, A);
  k_mfma<<<GBLK, 256, 0, stream>>>(A, WT2[0], bv[0], gout, pstat);
  k_bnred<<<256, 256, 0, stream>>>(pstat, stats);
  k_bnapply<<<XB4, 256, 0, stream>>>(gout, stats, g[0], be[0], A);

  // layer 1
  k_aggH<<<AB, 256, 0, stream>>>(row_ptr, er_s, A);
  k_mfma<<<GBLK, 256, 0, stream>>>(A, WT2[1], bv[1], gout, pstat);
  k_bnred<<<256, 256, 0, stream>>>(pstat, stats + 256);
  k_bnapply<<<XB4, 256, 0, stream>>>(gout, stats + 256, g[1], be[1], A);

  // layer 2
  k_l2_dense<<<AB, 256, 0, stream>>>(A, Wm[2], bm[2], Wr[2], br[2], val, pmb);
  k_agg2<<<NB, 256, 0, stream>>>(row_ptr, er_s, pmb, val);
  k_bnstats2<<<64, 256, 0, stream>>>(val, stats + 512);
  k_final<<<NB, 256, 0, stream>>>(val, stats + 512, g[2], be[2], out);
}

// Round 19
// 311.286 us; speedup vs baseline: 1.0319x; 1.0319x over previous
//
#include <hip/hip_runtime.h>
#include <math.h>

#define N_NODES 50000
#define N_EDGES 800000
#define DIN 128
#define DH 128
#define EA_C 50
#define DE 100
#define FM 228      // DIN + DE
#define AS 320      // A stride in u32
#define WKL 384     // logical K (W stride)
#define BM 32       // GEMM row tile
#define BN_EPS 1e-5f
#define SCAN_NB ((N_NODES + 255) / 256)   // 196
#define GBLK ((N_NODES + BM - 1) / BM)    // 1563
#define GSZ  ((N_NODES + 7) / 8)          // 6250 rows per XCD partition
#define EB   ((N_EDGES + 255) / 256)      // 3125
#define XB4  ((N_NODES * 32 + 255) / 256) // 6250
#define WB   ((DH * WKL + 255) / 256)     // 192

typedef __attribute__((ext_vector_type(8))) short short8;
typedef __attribute__((ext_vector_type(4))) short s16x4;
typedef __attribute__((ext_vector_type(4))) float f32x4;
typedef unsigned int u32;
typedef unsigned short u16;

// ---- bf16 hi/lo packing ----
__device__ inline u16 f2bf(float f) {
  u32 u = __float_as_uint(f);
  u32 r = (u + 0x7fffu + ((u >> 16) & 1u)) >> 16;
  return (u16)r;
}
__device__ inline float bf2f(u16 h) { return __uint_as_float(((u32)h) << 16); }
__device__ inline u32 pack_hl(float v) {
  u16 hi = f2bf(v);
  u16 lo = f2bf(v - bf2f(hi));
  return (u32)hi | ((u32)lo << 16);
}
__device__ inline float unpack_hl(u32 p) {
  return bf2f((u16)(p & 0xffffu)) + bf2f((u16)(p >> 16));
}

// ---------------- merged prep: edge count+payload | x -> h16 plane -----------
__global__ void k_prep_edges(const int* __restrict__ row, const int* __restrict__ col,
                             const int* __restrict__ attr, const int* __restrict__ dire,
                             const int* __restrict__ tim, const float* __restrict__ x,
                             int* __restrict__ counts, uint2* __restrict__ pay8,
                             u32* __restrict__ A) {
  int b = blockIdx.x;
  if (b < EB) {
    int e = b * 256 + threadIdx.x;
    if (e < N_EDGES) {
      atomicAdd(&counts[row[e]], 1);
      uint2 rec;
      rec.x = (u32)col[e] * AS | (((u32)attr[e] * 2 + (u32)dire[e]) << 24);
      rec.y = __float_as_uint(__logf((float)tim[e] + 1.0f));
      pay8[e] = rec;
    }
  } else {
    int idx = (b - EB) * 256 + threadIdx.x;
    if (idx >= N_NODES * 32) return;
    int n = idx >> 5, c4 = (idx & 31) << 2;
    float4 v = *reinterpret_cast<const float4*>(x + (size_t)n * DH + c4);
    uint2 o;
    o.x = (u32)f2bf(v.x) | ((u32)f2bf(v.y) << 16);
    o.y = (u32)f2bf(v.z) | ((u32)f2bf(v.w) << 16);
    *reinterpret_cast<uint2*>(A + (size_t)n * AS + 128 + (c4 >> 1)) = o;
  }
}

// ---------------- merged prep: W hi/lo packing x2 | biases | combined emb ----
__global__ void k_prep_w(const float* __restrict__ Wm0, const float* __restrict__ Wr0,
                         u32* __restrict__ WT0,
                         const float* __restrict__ Wm1, const float* __restrict__ Wr1,
                         u32* __restrict__ WT1,
                         const float* __restrict__ bm0, const float* __restrict__ br0,
                         float* __restrict__ bv0,
                         const float* __restrict__ bm1, const float* __restrict__ br1,
                         float* __restrict__ bv1,
                         const float* __restrict__ emb_type, const float* __restrict__ emb_dir,
                         float* __restrict__ ec) {
  int b = blockIdx.x;
  if (b < 2 * WB) {
    const float* Wm = (b < WB) ? Wm0 : Wm1;
    const float* Wr = (b < WB) ? Wr0 : Wr1;
    u32* WT = (b < WB) ? WT0 : WT1;
    int idx = (b < WB ? b : b - WB) * 256 + threadIdx.x;
    if (idx >= DH * WKL) return;
    int o = idx / WKL, k = idx - o * WKL;
    float v;
    if (k < 128) v = 0.5f * Wm[o * FM + k];
    else if (k < 256) v = Wr[o * DIN + (k - 128)];
    else if (k < 356) v = 0.5f * Wm[o * FM + (k - 128)];
    else v = 0.f;
    WT[idx] = pack_hl(v);
  } else {
    int t = threadIdx.x;
    if (t < 128) bv0[t] = 0.5f * bm0[t] + br0[t];
    else bv1[t - 128] = 0.5f * bm1[t - 128] + br1[t - 128];
    for (int i = t; i < 24 * EA_C; i += 256) {
      int combo = i / EA_C, l = i - combo * EA_C;
      ec[i] = emb_type[(combo >> 1) * EA_C + l] + emb_dir[(combo & 1) * EA_C + l];
    }
  }
}

__global__ void k_scan_a(const int* __restrict__ counts, int* __restrict__ incl,
                         int* __restrict__ bsum) {
  __shared__ int buf[256];
  int i = blockIdx.x * 256 + threadIdx.x;
  int v = (i < N_NODES) ? counts[i] : 0;
  buf[threadIdx.x] = v;
  __syncthreads();
#pragma unroll
  for (int off = 1; off < 256; off <<= 1) {
    int t = (threadIdx.x >= off) ? buf[threadIdx.x - off] : 0;
    __syncthreads();
    buf[threadIdx.x] += t;
    __syncthreads();
  }
  if (i < N_NODES) incl[i] = buf[threadIdx.x];
  if (threadIdx.x == 255) bsum[blockIdx.x] = buf[255];
}

__global__ void k_scan_b(const int* __restrict__ bsum, int* __restrict__ boff,
                         int* __restrict__ row_ptr) {
  __shared__ int buf[256];
  int v = (threadIdx.x < SCAN_NB) ? bsum[threadIdx.x] : 0;
  buf[threadIdx.x] = v;
  __syncthreads();
#pragma unroll
  for (int off = 1; off < 256; off <<= 1) {
    int t = (threadIdx.x >= off) ? buf[threadIdx.x - off] : 0;
    __syncthreads();
    buf[threadIdx.x] += t;
    __syncthreads();
  }
  if (threadIdx.x < SCAN_NB) boff[threadIdx.x] = buf[threadIdx.x] - v;
  if (threadIdx.x == 255) row_ptr[N_NODES] = buf[255];
}

__global__ void k_scan_c(const int* __restrict__ incl, const int* __restrict__ counts,
                         const int* __restrict__ boff, int* __restrict__ row_ptr,
                         int* __restrict__ cursor) {
  int i = blockIdx.x * 256 + threadIdx.x;
  if (i < N_NODES) {
    int p = incl[i] - counts[i] + boff[blockIdx.x];
    row_ptr[i] = p;
    cursor[i] = p;
  }
}

// XCD-partitioned scatter (r12)
__global__ void k_fill(const int* __restrict__ row, const uint2* __restrict__ pay8,
                       int* __restrict__ cursor, uint2* __restrict__ er_s) {
  int b = blockIdx.x;
  int g = b & 7, c = b >> 3;
  int e = c * 256 + threadIdx.x;
  if (e >= N_EDGES) return;
  int r = row[e];
  int lo = g * GSZ;
  if (r < lo || r >= lo + GSZ) return;
  int slot = atomicAdd(&cursor[r], 1);
  er_s[slot] = pay8[e];
}

// ---------------- FUSED layer-0 aggregation: h-agg + ea + et -----------------
__global__ void k_aggHE(const int* __restrict__ row_ptr, const uint2* __restrict__ er_s,
                        const float* __restrict__ ec,
                        const float* __restrict__ w_t, const float* __restrict__ b_t,
                        u32* __restrict__ A) {
  int wave = threadIdx.x >> 6, lane = threadIdx.x & 63;
  int n = blockIdx.x * 4 + wave;
  if (n >= N_NODES) return;
  int s = __builtin_amdgcn_readfirstlane(row_ptr[n]);
  int epos = __builtin_amdgcn_readfirstlane(row_ptr[n + 1]);
  bool ew = lane < EA_C;
  float wt = ew ? w_t[lane] : 0.f;
  float bt = ew ? b_t[lane] : 0.f;
  float ax = 0.f, ay = 0.f, ea = 0.f, et = 0.f;
  int p = s;
  for (; p + 3 < epos; p += 4) {
    uint2 r0 = er_s[p], r1 = er_s[p + 1], r2 = er_s[p + 2], r3 = er_s[p + 3];
    u32 v0 = A[(r0.x & 0xFFFFFFu) + 128 + lane];
    u32 v1 = A[(r1.x & 0xFFFFFFu) + 128 + lane];
    u32 v2 = A[(r2.x & 0xFFFFFFu) + 128 + lane];
    u32 v3 = A[(r3.x & 0xFFFFFFu) + 128 + lane];
    if (ew) {
      ea += ec[(r0.x >> 24) * EA_C + lane] + ec[(r1.x >> 24) * EA_C + lane];
      ea += ec[(r2.x >> 24) * EA_C + lane] + ec[(r3.x >> 24) * EA_C + lane];
      et += __cosf(__uint_as_float(r0.y) * wt + bt) + __cosf(__uint_as_float(r1.y) * wt + bt);
      et += __cosf(__uint_as_float(r2.y) * wt + bt) + __cosf(__uint_as_float(r3.y) * wt + bt);
    }
    ax += bf2f((u16)(v0 & 0xffffu)) + bf2f((u16)(v1 & 0xffffu)) +
          bf2f((u16)(v2 & 0xffffu)) + bf2f((u16)(v3 & 0xffffu));
    ay += bf2f((u16)(v0 >> 16)) + bf2f((u16)(v1 >> 16)) +
          bf2f((u16)(v2 >> 16)) + bf2f((u16)(v3 >> 16));
  }
  for (; p < epos; ++p) {
    uint2 r0 = er_s[p];
    u32 v0 = A[(r0.x & 0xFFFFFFu) + 128 + lane];
    if (ew) {
      ea += ec[(r0.x >> 24) * EA_C + lane];
      et += __cosf(__uint_as_float(r0.y) * wt + bt);
    }
    ax += bf2f((u16)(v0 & 0xffffu));
    ay += bf2f((u16)(v0 >> 16));
  }
  uint2 o; o.x = pack_hl(ax); o.y = pack_hl(ay);
  *reinterpret_cast<uint2*>(A + (size_t)n * AS + 2 * lane) = o;
  if (ew) {
    A[(size_t)n * AS + 192 + lane] = pack_hl(ea);
    A[(size_t)n * AS + 242 + lane] = pack_hl(et);
  } else {
    int l = lane - EA_C;
    A[(size_t)n * AS + 292 + l] = 0u;
    A[(size_t)n * AS + 306 + l] = 0u;
  }
}

// ---------------- lean neighbor aggregation (layer 1), 8-edge unroll ---------
__global__ void k_aggH(const int* __restrict__ row_ptr, const uint2* __restrict__ er_s,
                       u32* __restrict__ A) {
  int wave = threadIdx.x >> 6, lane = threadIdx.x & 63;
  int n = blockIdx.x * 4 + wave;
  if (n >= N_NODES) return;
  int s = __builtin_amdgcn_readfirstlane(row_ptr[n]);
  int epos = __builtin_amdgcn_readfirstlane(row_ptr[n + 1]);
  float ax = 0.f, ay = 0.f;
  int p = s;
  for (; p + 7 < epos; p += 8) {
    u32 v[8];
#pragma unroll
    for (int j = 0; j < 8; ++j) v[j] = A[(er_s[p + j].x & 0xFFFFFFu) + 128 + lane];
#pragma unroll
    for (int j = 0; j < 8; ++j) {
      ax += bf2f((u16)(v[j] & 0xffffu));
      ay += bf2f((u16)(v[j] >> 16));
    }
  }
  for (; p < epos; ++p) {
    u32 v = A[(er_s[p].x & 0xFFFFFFu) + 128 + lane];
    ax += bf2f((u16)(v & 0xffffu));
    ay += bf2f((u16)(v >> 16));
  }
  uint2 o; o.x = pack_hl(ax); o.y = pack_hl(ay);
  *reinterpret_cast<uint2*>(A + (size_t)n * AS + 2 * lane) = o;
}

// ---------------- MFMA GEMM: BM=32, granule-transposed LDS (r17 best) --------
__global__ __launch_bounds__(256) void k_mfma(const u32* __restrict__ A,
                                              const u32* __restrict__ W,
                                              const float* __restrict__ bv,
                                              float* __restrict__ out,
                                              float* __restrict__ pstat) {
  __shared__ u16 Ah[4][BM][8], Al[4][BM][8];     // 2KB each
  __shared__ u16 Wh[4][128][8], Wl[4][128][8];   // 8KB each
  __shared__ float sred[4][128], qred[4][128];
  int tid = threadIdx.x;
  int wv = tid >> 6, ln = tid & 63;
  int rw = wv >> 1, cw = wv & 1;
  int colb = ln & 15, fq = ln >> 4;
  int node0 = blockIdx.x * BM;

  {
    float* sp = &sred[0][0]; float* qp = &qred[0][0];
    sp[tid] = 0.f; sp[tid + 256] = 0.f;
    qp[tid] = 0.f; qp[tid + 256] = 0.f;
  }

  f32x4 acc[4];
#pragma unroll
  for (int nt = 0; nt < 4; ++nt) acc[nt] = (f32x4){0.f, 0.f, 0.f, 0.f};

  int ar = tid >> 3, aq = tid & 7;
  int an = node0 + ar;
  bool valid = an < N_NODES;
  const u32* aptr = A + (size_t)an * AS;
  int wc = tid >> 1, wk = (tid & 1) * 16;
  int wg = (tid & 1) * 2;
  const u32* wptr = W + (size_t)wc * WKL + wk;

  const u16* afh = &Ah[fq][(rw << 4) + colb][0];
  const u16* afl = &Al[fq][(rw << 4) + colb][0];

#pragma unroll
  for (int ch = 0; ch < 12; ++ch) {
    const int kl = ch * 32;
    const bool ph2 = (ch >= 4 && ch < 8);
    uint4 a0 = make_uint4(0, 0, 0, 0);
    if (!ph2) {
      int acol = (ch < 4 ? kl : kl - 64) + aq * 4;
      if (valid) a0 = *reinterpret_cast<const uint4*>(aptr + acol);
    } else if (aq < 4) {
      int acol = 128 + ((kl - 128) >> 1) + aq * 4;
      if (valid) a0 = *reinterpret_cast<const uint4*>(aptr + acol);
    }
    uint4 w0 = *reinterpret_cast<const uint4*>(wptr + kl);
    uint4 w1 = *reinterpret_cast<const uint4*>(wptr + kl + 4);
    uint4 w2 = *reinterpret_cast<const uint4*>(wptr + kl + 8);
    uint4 w3 = *reinterpret_cast<const uint4*>(wptr + kl + 12);

    __syncthreads();   // previous chunk's LDS reads done

    if (!ph2) {
      u32 va[4] = {a0.x, a0.y, a0.z, a0.w};
      s16x4 h, l;
#pragma unroll
      for (int j = 0; j < 4; ++j) { h[j] = (short)(va[j] & 0xffffu); l[j] = (short)(va[j] >> 16); }
      *reinterpret_cast<s16x4*>(&Ah[aq >> 1][ar][(aq & 1) * 4]) = h;
      *reinterpret_cast<s16x4*>(&Al[aq >> 1][ar][(aq & 1) * 4]) = l;
    } else if (aq < 4) {
      *reinterpret_cast<short8*>(&Ah[aq][ar][0]) = *reinterpret_cast<const short8*>(&a0);
    }
    {
      u32 vw[16] = {w0.x, w0.y, w0.z, w0.w, w1.x, w1.y, w1.z, w1.w,
                    w2.x, w2.y, w2.z, w2.w, w3.x, w3.y, w3.z, w3.w};
      short8 h0, l0, h1, l1;
#pragma unroll
      for (int j = 0; j < 8; ++j) {
        h0[j] = (short)(vw[j] & 0xffffu);     l0[j] = (short)(vw[j] >> 16);
        h1[j] = (short)(vw[j + 8] & 0xffffu); l1[j] = (short)(vw[j + 8] >> 16);
      }
      *reinterpret_cast<short8*>(&Wh[wg][wc][0]) = h0;
      *reinterpret_cast<short8*>(&Wh[wg + 1][wc][0]) = h1;
      *reinterpret_cast<short8*>(&Wl[wg][wc][0]) = l0;
      *reinterpret_cast<short8*>(&Wl[wg + 1][wc][0]) = l1;
    }

    __syncthreads();   // LDS writes visible

    short8 ah = *reinterpret_cast<const short8*>(afh);
    short8 al = *reinterpret_cast<const short8*>(afl);
#pragma unroll
    for (int nt = 0; nt < 4; ++nt) {
      int wrow = (cw << 6) + nt * 16 + colb;
      short8 bh = *reinterpret_cast<const short8*>(&Wh[fq][wrow][0]);
      short8 bl = *reinterpret_cast<const short8*>(&Wl[fq][wrow][0]);
      acc[nt] = __builtin_amdgcn_mfma_f32_16x16x32_bf16(ah, bh, acc[nt], 0, 0, 0);
      if (!ph2) acc[nt] = __builtin_amdgcn_mfma_f32_16x16x32_bf16(al, bh, acc[nt], 0, 0, 0);
      acc[nt] = __builtin_amdgcn_mfma_f32_16x16x32_bf16(ah, bl, acc[nt], 0, 0, 0);
    }
  }

  // epilogue: out + bias; BN partials shuffle-reduced, NO atomics
  int rbase = node0 + (rw << 4) + (fq << 2);
#pragma unroll
  for (int nt = 0; nt < 4; ++nt) {
    int col = (cw << 6) + nt * 16 + colb;
    float bb = bv[col];
    float s = 0.f, q = 0.f;
#pragma unroll
    for (int r = 0; r < 4; ++r) {
      int n = rbase + r;
      if (n < N_NODES) {
        float v = acc[nt][r] + bb;
        out[(size_t)n * DH + col] = v;
        s += v; q += v * v;
      }
    }
    s += __shfl_xor(s, 16, 64); s += __shfl_xor(s, 32, 64);
    q += __shfl_xor(q, 16, 64); q += __shfl_xor(q, 32, 64);
    if (fq == 0) { sred[wv][col] = s; qred[wv][col] = q; }
  }
  __syncthreads();
  if (tid < 128) {
    float s = sred[0][tid] + sred[1][tid] + sred[2][tid] + sred[3][tid];
    float q = qred[0][tid] + qred[1][tid] + qred[2][tid] + qred[3][tid];
    pstat[(size_t)blockIdx.x * 256 + tid] = s;
    pstat[(size_t)blockIdx.x * 256 + 128 + tid] = q;
  }
}

// reduce per-block partials -> stats[256]
__global__ void k_bnred(const float* __restrict__ pstat, float* __restrict__ stats) {
  __shared__ float red[256];
  int slot = blockIdx.x;
  float s = 0.f;
  for (int b = threadIdx.x; b < GBLK; b += 256) s += pstat[(size_t)b * 256 + slot];
  red[threadIdx.x] = s;
  __syncthreads();
  for (int off = 128; off >= 1; off >>= 1) {
    if (threadIdx.x < off) red[threadIdx.x] += red[threadIdx.x + off];
    __syncthreads();
  }
  if (threadIdx.x == 0) stats[slot] = red[0];
}

// BN + ELU -> h16 plane (bf16), x4 vectorized
__global__ void k_bnapply(const float* __restrict__ x, const float* __restrict__ stats,
                          const float* __restrict__ g, const float* __restrict__ be,
                          u32* __restrict__ A) {
  int idx = blockIdx.x * 256 + threadIdx.x;
  if (idx >= N_NODES * 32) return;
  int n = idx >> 5, c4 = (idx & 31) << 2;
  float4 v = *reinterpret_cast<const float4*>(x + (size_t)n * DH + c4);
  float4 sm = *reinterpret_cast<const float4*>(stats + c4);
  float4 sq = *reinterpret_cast<const float4*>(stats + 128 + c4);
  float4 gg = *reinterpret_cast<const float4*>(g + c4);
  float4 bb = *reinterpret_cast<const float4*>(be + c4);
  float vv[4] = {v.x, v.y, v.z, v.w};
  float mm[4] = {sm.x, sm.y, sm.z, sm.w};
  float qq[4] = {sq.x, sq.y, sq.z, sq.w};
  float ga[4] = {gg.x, gg.y, gg.z, gg.w};
  float ba[4] = {bb.x, bb.y, bb.z, bb.w};
  u16 ob[4];
#pragma unroll
  for (int j = 0; j < 4; ++j) {
    float mu = mm[j] * (1.0f / N_NODES);
    float var = qq[j] * (1.0f / N_NODES) - mu * mu;
    float y = (vv[j] - mu) * rsqrtf(var + BN_EPS) * ga[j] + ba[j];
    y = y > 0.f ? y : expm1f(y);
    ob[j] = f2bf(y);
  }
  uint2 o;
  o.x = (u32)ob[0] | ((u32)ob[1] << 16);
  o.y = (u32)ob[2] | ((u32)ob[3] << 16);
  *reinterpret_cast<uint2*>(A + (size_t)n * AS + 128 + (c4 >> 1)) = o;
}

// ---------------- layer 2 (project-first, dout=2) ----------------
__global__ void k_l2_dense(const u32* __restrict__ A,
                           const float* __restrict__ Wm2, const float* __restrict__ bm2,
                           const float* __restrict__ Wr2, const float* __restrict__ br2,
                           float* __restrict__ val, float* __restrict__ pm) {
  int wave = threadIdx.x >> 6, lane = threadIdx.x & 63;
  int n = blockIdx.x * 4 + wave;
  if (n >= N_NODES) return;
  const u32* ar = A + (size_t)n * AS;
  const u16* h16 = (const u16*)(ar + 128);
  float h0 = bf2f(h16[lane]);
  float h1 = bf2f(h16[lane + 64]);
  float e0 = unpack_hl(ar[192 + lane]);
  float e1 = (lane < DE - 64) ? unpack_hl(ar[256 + lane]) : 0.f;

  float pm0 = h0 * Wm2[lane] + h1 * Wm2[lane + 64];
  float pm1 = h0 * Wm2[FM + lane] + h1 * Wm2[FM + lane + 64];
  float ve0 = e0 * Wm2[DIN + lane] + ((lane < DE - 64) ? e1 * Wm2[DIN + lane + 64] : 0.f);
  float ve1 = e0 * Wm2[FM + DIN + lane] + ((lane < DE - 64) ? e1 * Wm2[FM + DIN + lane + 64] : 0.f);
  float pr0 = h0 * Wr2[lane] + h1 * Wr2[lane + 64];
  float pr1 = h0 * Wr2[DH + lane] + h1 * Wr2[DH + lane + 64];

#pragma unroll
  for (int m = 32; m >= 1; m >>= 1) {
    pm0 += __shfl_xor(pm0, m, 64); pm1 += __shfl_xor(pm1, m, 64);
    ve0 += __shfl_xor(ve0, m, 64); ve1 += __shfl_xor(ve1, m, 64);
    pr0 += __shfl_xor(pr0, m, 64); pr1 += __shfl_xor(pr1, m, 64);
  }
  if (lane == 0) {
    val[n * 2 + 0] = 0.5f * (ve0 + bm2[0]) + pr0 + br2[0];
    val[n * 2 + 1] = 0.5f * (ve1 + bm2[1]) + pr1 + br2[1];
    pm[n * 2 + 0] = pm0;
    pm[n * 2 + 1] = pm1;
  }
}

__global__ void k_agg2(const int* __restrict__ row_ptr, const uint2* __restrict__ er_s,
                       const float* __restrict__ pm, float* __restrict__ val) {
  int n = blockIdx.x * 256 + threadIdx.x;
  if (n >= N_NODES) return;
  float a0 = 0.f, a1 = 0.f;
  int s = row_ptr[n], e = row_ptr[n + 1];
  for (int p = s; p < e; ++p) {
    u32 coff = er_s[p].x & 0xFFFFFFu;
    u32 c = __umulhi(coff >> 6, 0xCCCCCCCDu) >> 2;   // (coff/64)/5 = col
    a0 += pm[c * 2]; a1 += pm[c * 2 + 1];
  }
  val[n * 2] += 0.5f * a0;
  val[n * 2 + 1] += 0.5f * a1;
}

__global__ void k_bnstats2(const float* __restrict__ val, float* __restrict__ s4) {
  float s0 = 0.f, q0 = 0.f, s1 = 0.f, q1 = 0.f;
  for (int n = blockIdx.x * 256 + threadIdx.x; n < N_NODES; n += gridDim.x * 256) {
    float v0 = val[n * 2], v1 = val[n * 2 + 1];
    s0 += v0; q0 += v0 * v0; s1 += v1; q1 += v1 * v1;
  }
  __shared__ float b[256][4];
  b[threadIdx.x][0] = s0; b[threadIdx.x][1] = q0;
  b[threadIdx.x][2] = s1; b[threadIdx.x][3] = q1;
  __syncthreads();
  for (int off = 128; off >= 1; off >>= 1) {
    if (threadIdx.x < off)
      for (int j = 0; j < 4; ++j) b[threadIdx.x][j] += b[threadIdx.x + off][j];
    __syncthreads();
  }
  if (threadIdx.x == 0)
    for (int j = 0; j < 4; ++j) atomicAdd(&s4[j], b[0][j]);
}

__global__ void k_final(const float* __restrict__ val, const float* __restrict__ s4,
                        const float* __restrict__ g2, const float* __restrict__ be2,
                        float* __restrict__ out) {
  int n = blockIdx.x * 256 + threadIdx.x;
  if (n >= N_NODES) return;
  float mu0 = s4[0] * (1.f / N_NODES), var0 = s4[1] * (1.f / N_NODES) - mu0 * mu0;
  float mu1 = s4[2] * (1.f / N_NODES), var1 = s4[3] * (1.f / N_NODES) - mu1 * mu1;
  float y0 = (val[n * 2] - mu0) * rsqrtf(var0 + BN_EPS) * g2[0] + be2[0];
  float y1 = (val[n * 2 + 1] - mu1) * rsqrtf(var1 + BN_EPS) * g2[1] + be2[1];
  float m = fmaxf(y0, y1);
  float lse = m + __logf(__expf(y0 - m) + __expf(y1 - m));
  out[n * 2] = y0 - lse;
  out[n * 2 + 1] = y1 - lse;
}

// ---------------- launch ----------------
extern "C" void kernel_launch(void* const* d_in, const int* in_sizes, int n_in,
                              void* d_out, int out_size, void* d_ws, size_t ws_size,
                              hipStream_t stream) {
  (void)in_sizes; (void)n_in; (void)out_size; (void)ws_size;
  const float* x        = (const float*)d_in[0];
  const int*   eidx     = (const int*)d_in[1];
  const int*   row      = eidx;
  const int*   col      = eidx + N_EDGES;
  const int*   attr     = (const int*)d_in[2];
  const int*   tim      = (const int*)d_in[3];
  const int*   dire     = (const int*)d_in[4];
  const float* emb_type = (const float*)d_in[5];
  const float* emb_dir  = (const float*)d_in[6];
  const float* w_t      = (const float*)d_in[7];
  const float* b_t      = (const float*)d_in[8];
  const float* Wm[3] = {(const float*)d_in[9],  (const float*)d_in[15], (const float*)d_in[21]};
  const float* bm[3] = {(const float*)d_in[10], (const float*)d_in[16], (const float*)d_in[22]};
  const float* Wr[3] = {(const float*)d_in[11], (const float*)d_in[17], (const float*)d_in[23]};
  const float* br[3] = {(const float*)d_in[12], (const float*)d_in[18], (const float*)d_in[24]};
  const float* g[3]  = {(const float*)d_in[13], (const float*)d_in[19], (const float*)d_in[25]};
  const float* be[3] = {(const float*)d_in[14], (const float*)d_in[20], (const float*)d_in[26]};
  float* out = (float*)d_out;

  // workspace layout (~99 MB)
  char* p = (char*)d_ws;
  u32* A     = (u32*)p;   p += sizeof(u32) * (size_t)N_NODES * AS;    // 64 MB
  float* gout = (float*)p; p += sizeof(float) * (size_t)N_NODES * DH; // 25.6 MB
  uint2* er_s = (uint2*)p; p += sizeof(uint2) * (size_t)N_EDGES;      // 6.4 MB
  float* pstat = (float*)p; p += sizeof(float) * (size_t)GBLK * 256;  // 1.6 MB
  u32* WT2[2];
  WT2[0] = (u32*)p; p += sizeof(u32) * DH * WKL;
  WT2[1] = (u32*)p; p += sizeof(u32) * DH * WKL;
  float* bv[2];
  bv[0] = (float*)p; p += sizeof(float) * DH;
  bv[1] = (float*)p; p += sizeof(float) * DH;
  float* ec   = (float*)p;  p += sizeof(float) * 24 * EA_C;
  float* val  = (float*)p;  p += sizeof(float) * (size_t)N_NODES * 2;
  float* pmb  = (float*)p;  p += sizeof(float) * (size_t)N_NODES * 2;
  float* stats = (float*)p; p += sizeof(float) * 520;
  int* counts  = (int*)p;   p += sizeof(int) * N_NODES;
  int* cursor  = (int*)p;   p += sizeof(int) * N_NODES;
  int* row_ptr = (int*)p;   p += sizeof(int) * (N_NODES + 1);
  int* incl    = (int*)p;   p += sizeof(int) * N_NODES;
  int* bsum    = (int*)p;   p += sizeof(int) * SCAN_NB;
  int* boff    = (int*)p;   p += sizeof(int) * SCAN_NB;

  uint2* pay8 = (uint2*)gout;   // aliases gout (consumed by k_fill before k_mfma writes)

  const int NB = (N_NODES + 255) / 256;      // 196
  const int AB = (N_NODES + 3) / 4;          // 12500

  hipMemsetAsync(counts, 0, sizeof(int) * N_NODES, stream);
  hipMemsetAsync(stats, 0, sizeof(float) * 520, stream);

  // merged prep: edges (count+payload) + x->h16 plane ; weights + biases + ec
  k_prep_edges<<<EB + XB4, 256, 0, stream>>>(row, col, attr, dire, tim, x, counts, pay8, A);
  k_prep_w<<<2 * WB + 1, 256, 0, stream>>>(Wm[0], Wr[0], WT2[0], Wm[1], Wr[1], WT2[1],
                                           bm[0], br[0], bv[0], bm[1], br[1], bv[1],
                                           emb_type, emb_dir, ec);

  // CSR
  k_scan_a<<<SCAN_NB, 256, 0, stream>>>(counts, incl, bsum);
  k_scan_b<<<1, 256, 0, stream>>>(bsum, boff, row_ptr);
  k_scan_c<<<SCAN_NB, 256, 0, stream>>>(incl, counts, boff, row_ptr, cursor);
  k_fill<<<8 * EB, 256, 0, stream>>>(row, pay8, cursor, er_s);

  // layer 0: fused h-agg + edge-feature agg
  k_aggHE<<<AB, 256, 0, stream>>>(row_ptr, er_s, ec, w_t, b_t, A);
  k_mfma<<<GBLK, 256, 0, stream>>>(A, WT2[0], bv[0], gout, pstat);
  k_bnred<<<256, 256, 0, stream>>>(pstat, stats);
  k_bnapply<<<XB4, 256, 0, stream>>>(gout, stats, g[0], be[0], A);

  // layer 1
  k_aggH<<<AB, 256, 0, stream>>>(row_ptr, er_s, A);
  k_mfma<<<GBLK, 256, 0, stream>>>(A, WT2[1], bv[1], gout, pstat);
  k_bnred<<<256, 256, 0, stream>>>(pstat, stats + 256);
  k_bnapply<<<XB4, 256, 0, stream>>>(gout, stats + 256, g[1], be[1], A);

  // layer 2
  k_l2_dense<<<AB, 256, 0, stream>>>(A, Wm[2], bm[2], Wr[2], br[2], val, pmb);
  k_agg2<<<NB, 256, 0, stream>>>(row_ptr, er_s, pmb, val);
  k_bnstats2<<<64, 256, 0, stream>>>(val, stats + 512);
  k_final<<<NB, 256, 0, stream>>>(val, stats + 512, g[2], be[2], out);
}